// Round 1
// baseline (377.944 us; speedup 1.0000x reference)
//
#include <hip/hip_runtime.h>

#define N_NODES 50000
#define N_EDGES 800000
#define CAP 48
// IN_F = 64, OUT_F = 64, EDGE_F = 16, d_in1 = 144
// NOTE: harness passes ALL integer inputs as int32 — edge_index is int32[2*E],
// src = ei[e], dst = ei[E+e].

// ---------------------------------------------------------------------------
// pre_kernel: xa = x @ W1[0:64,:], xb = x @ W1[64:128,:]   (N x 64 each)
// ---------------------------------------------------------------------------
__global__ __launch_bounds__(256) void pre_kernel(
    const float* __restrict__ x, const float* __restrict__ W1,
    float* __restrict__ xa, float* __restrict__ xb)
{
    const int w = threadIdx.x >> 6;
    const int j = threadIdx.x & 63;
    const int gw = blockIdx.x * 4 + w;
    const int p = gw & 1;
    const int pair = gw >> 1;
    const int npair = (gridDim.x * 4) >> 1;

    float wc[64];
#pragma unroll
    for (int k = 0; k < 64; ++k) wc[k] = W1[(p * 64 + k) * 64 + j];

    float* __restrict__ outp = p ? xb : xa;

    for (int i = pair; i < N_NODES; i += npair) {
        const float4* xr = (const float4*)&x[(size_t)i * 64];
        float acc = 0.f;
#pragma unroll
        for (int k4 = 0; k4 < 16; ++k4) {
            float4 xv = xr[k4];
            acc += xv.x * wc[k4 * 4 + 0];
            acc += xv.y * wc[k4 * 4 + 1];
            acc += xv.z * wc[k4 * 4 + 2];
            acc += xv.w * wc[k4 * 4 + 3];
        }
        outp[(size_t)i * 64 + j] = acc;
    }
}

// ---------------------------------------------------------------------------
// build_kernel: bucket edges by dst. slot[d*CAP+pos] = (src, e).
// Overflow (pos >= CAP) edges go to oflow list (expected empty: deg~Poisson(16)).
// ---------------------------------------------------------------------------
__global__ __launch_bounds__(256) void build_kernel(
    const int* __restrict__ ei, unsigned* __restrict__ cnt,
    unsigned* __restrict__ ocnt, uint2* __restrict__ slot,
    unsigned* __restrict__ oflow)
{
    const int e = blockIdx.x * 256 + threadIdx.x;
    const int s = ei[e];
    const int d = ei[N_EDGES + e];
    const unsigned pos = atomicAdd(&cnt[d], 1u);
    if (pos < CAP) {
        slot[(size_t)d * CAP + pos] = make_uint2((unsigned)s, (unsigned)e);
    } else {
        const unsigned oi = atomicAdd(ocnt, 1u);
        oflow[oi] = (unsigned)e;
    }
}

// ---------------------------------------------------------------------------
// node_kernel: one wave per dst node. hsum[n] = sum_e relu(xa[src]+xb[n]+ea@W1c+b1)
// No atomics, no LDS. 2-stage software pipeline: slot -> (ea, xa) skewed.
// ---------------------------------------------------------------------------
__global__ __launch_bounds__(256) void node_kernel(
    const float* __restrict__ xa, const float* __restrict__ xb,
    const float* __restrict__ ea, const uint2* __restrict__ slot,
    const unsigned* __restrict__ cnt,
    const float* __restrict__ W1, const float* __restrict__ b1,
    float* __restrict__ hsum)
{
    const int w = threadIdx.x >> 6;
    const int j = threadIdx.x & 63;
    const int n = blockIdx.x * 4 + w;

    float w1c[16];
#pragma unroll
    for (int k = 0; k < 16; ++k) w1c[k] = W1[(128 + k) * 64 + j];
    const float base = xb[(size_t)n * 64 + j] + b1[j];

    int d = (int)cnt[n];
    const int dcap = d < CAP ? d : CAP;
    const uint2* __restrict__ sl = &slot[(size_t)n * CAP];

    float hacc = 0.f;
    if (dcap > 0) {
        uint2 nxt = sl[0];
        float4 s0 = *(const float4*)&ea[(size_t)nxt.y * 16 + 0];
        float4 s1 = *(const float4*)&ea[(size_t)nxt.y * 16 + 4];
        float4 s2 = *(const float4*)&ea[(size_t)nxt.y * 16 + 8];
        float4 s3 = *(const float4*)&ea[(size_t)nxt.y * 16 + 12];
        float sx = xa[(size_t)nxt.x * 64 + j];
        if (dcap > 1) nxt = sl[1];
        for (int i = 0; i < dcap; ++i) {
            const float4 c0 = s0, c1 = s1, c2 = s2, c3 = s3;
            const float cx = sx;
            if (i + 1 < dcap) {
                s0 = *(const float4*)&ea[(size_t)nxt.y * 16 + 0];
                s1 = *(const float4*)&ea[(size_t)nxt.y * 16 + 4];
                s2 = *(const float4*)&ea[(size_t)nxt.y * 16 + 8];
                s3 = *(const float4*)&ea[(size_t)nxt.y * 16 + 12];
                sx = xa[(size_t)nxt.x * 64 + j];
                if (i + 2 < dcap) nxt = sl[i + 2];
            }
            float acc = base + cx;
            acc += c0.x * w1c[0];  acc += c0.y * w1c[1];
            acc += c0.z * w1c[2];  acc += c0.w * w1c[3];
            acc += c1.x * w1c[4];  acc += c1.y * w1c[5];
            acc += c1.z * w1c[6];  acc += c1.w * w1c[7];
            acc += c2.x * w1c[8];  acc += c2.y * w1c[9];
            acc += c2.z * w1c[10]; acc += c2.w * w1c[11];
            acc += c3.x * w1c[12]; acc += c3.y * w1c[13];
            acc += c3.z * w1c[14]; acc += c3.w * w1c[15];
            hacc += fmaxf(acc, 0.f);
        }
    }
    hsum[(size_t)n * 64 + j] = hacc;
}

// ---------------------------------------------------------------------------
// post_kernel: out[n] = hsum[n] @ W2 + min(cnt[n],CAP) * b2   (W2 hoisted out of
// the segment-sum by linearity). Writes every node -> no out memset needed.
// ---------------------------------------------------------------------------
__global__ __launch_bounds__(256) void post_kernel(
    const float* __restrict__ hsum, const unsigned* __restrict__ cnt,
    const float* __restrict__ W2, const float* __restrict__ b2,
    float* __restrict__ out)
{
    const int w = threadIdx.x >> 6;
    const int j = threadIdx.x & 63;
    const int gw = blockIdx.x * 4 + w;
    const int nw = gridDim.x * 4;

    float w2c[64];
#pragma unroll
    for (int k = 0; k < 64; ++k) w2c[k] = W2[k * 64 + j];
    const float b2j = b2[j];

    for (int n = gw; n < N_NODES; n += nw) {
        const float4* hr = (const float4*)&hsum[(size_t)n * 64];
        float acc = 0.f;
#pragma unroll
        for (int k4 = 0; k4 < 16; ++k4) {
            float4 hv = hr[k4];
            acc += hv.x * w2c[k4 * 4 + 0];
            acc += hv.y * w2c[k4 * 4 + 1];
            acc += hv.z * w2c[k4 * 4 + 2];
            acc += hv.w * w2c[k4 * 4 + 3];
        }
        int d = (int)cnt[n];
        d = d < CAP ? d : CAP;
        out[(size_t)n * 64 + j] = acc + (float)d * b2j;
    }
}

// ---------------------------------------------------------------------------
// overflow_kernel: correctness net for pos >= CAP edges (expected 0 edges).
// One wave per overflow edge; runs AFTER post_kernel; adds its own b2.
// ---------------------------------------------------------------------------
__global__ __launch_bounds__(256) void overflow_kernel(
    const float* __restrict__ xa, const float* __restrict__ xb,
    const int* __restrict__ ei, const float* __restrict__ ea,
    const float* __restrict__ W1, const float* __restrict__ b1,
    const float* __restrict__ W2, const float* __restrict__ b2,
    const unsigned* __restrict__ ocnt, const unsigned* __restrict__ oflow,
    float* __restrict__ out)
{
    const unsigned oc = *ocnt;
    if (oc == 0) return;
    const int w = threadIdx.x >> 6;
    const int j = threadIdx.x & 63;
    unsigned idx = blockIdx.x * 4 + w;
    const unsigned stride = gridDim.x * 4;
    for (; idx < oc; idx += stride) {
        const int e = (int)oflow[idx];
        const int s = ei[e];
        const int dd = ei[N_EDGES + e];
        float acc = xa[(size_t)s * 64 + j] + xb[(size_t)dd * 64 + j] + b1[j];
        for (int k = 0; k < 16; ++k)
            acc += ea[(size_t)e * 16 + k] * W1[(128 + k) * 64 + j];
        const float h = fmaxf(acc, 0.f);
        float msg = b2[j];
        for (int k = 0; k < 64; ++k) msg += __shfl(h, k) * W2[k * 64 + j];
        unsafeAtomicAdd(&out[(size_t)dd * 64 + j], msg);
    }
}

// ---------------------------------------------------------------------------
// OLD PATH (ws too small for bucketed pipeline): per-edge kernel with atomics.
// ---------------------------------------------------------------------------
__global__ __launch_bounds__(256) void edge_kernel(
    const float* __restrict__ xa, const float* __restrict__ xb,
    const int* __restrict__ ei,
    const float* __restrict__ edge_attr,
    const float* __restrict__ W1, const float* __restrict__ b1,
    const float* __restrict__ W2, const float* __restrict__ b2,
    float* __restrict__ out)
{
    __shared__ __align__(16) float eas[4][256];
    __shared__ __align__(16) float hs[4][16][64];

    const int w = threadIdx.x >> 6;
    const int j = threadIdx.x & 63;
    const int wt = blockIdx.x * 4 + w;
    const long eb = (long)wt * 16;

    float w1c[16];
    float w2c[64];
#pragma unroll
    for (int k = 0; k < 16; ++k) w1c[k] = W1[(128 + k) * 64 + j];
#pragma unroll
    for (int k = 0; k < 64; ++k) w2c[k] = W2[k * 64 + j];
    const float b1j = b1[j];
    const float b2j = b2[j];

    int idxv = 0;
    if (j < 16)       idxv = ei[eb + j];
    else if (j < 32)  idxv = ei[(long)N_EDGES + eb + (j - 16)];

    {
        float4 ev = *(const float4*)&edge_attr[eb * 16 + j * 4];
        *(float4*)&eas[w][j * 4] = ev;
    }

#pragma unroll 4
    for (int e = 0; e < 16; ++e) {
        const int s  = __shfl(idxv, e);
        const int dd = __shfl(idxv, 16 + e);

        float acc = xa[(long)s * 64 + j] + xb[(long)dd * 64 + j] + b1j;
#pragma unroll
        for (int k4 = 0; k4 < 4; ++k4) {
            float4 ev = *(const float4*)&eas[w][e * 16 + k4 * 4];
            acc += ev.x * w1c[k4 * 4 + 0];
            acc += ev.y * w1c[k4 * 4 + 1];
            acc += ev.z * w1c[k4 * 4 + 2];
            acc += ev.w * w1c[k4 * 4 + 3];
        }
        const float h = fmaxf(acc, 0.f);
        hs[w][e][j] = h;

        float msg = b2j;
#pragma unroll
        for (int k4 = 0; k4 < 16; ++k4) {
            float4 hv = *(const float4*)&hs[w][e][k4 * 4];
            msg += hv.x * w2c[k4 * 4 + 0];
            msg += hv.y * w2c[k4 * 4 + 1];
            msg += hv.z * w2c[k4 * 4 + 2];
            msg += hv.w * w2c[k4 * 4 + 3];
        }
        unsafeAtomicAdd(&out[(long)dd * 64 + j], msg);
    }
}

// ---------------------------------------------------------------------------
// fallback (only if ws tiny): one wave per edge, full 144-dot, shfl GEMM2
// ---------------------------------------------------------------------------
__global__ __launch_bounds__(256) void fallback_kernel(
    const float* __restrict__ x, const int* __restrict__ ei,
    const float* __restrict__ edge_attr,
    const float* __restrict__ W1, const float* __restrict__ b1,
    const float* __restrict__ W2, const float* __restrict__ b2,
    float* __restrict__ out)
{
    const int w = threadIdx.x >> 6;
    const int j = threadIdx.x & 63;
    const long e = (long)blockIdx.x * 4 + w;
    if (e >= N_EDGES) return;
    const int s  = ei[e];
    const int dd = ei[(long)N_EDGES + e];

    float acc = b1[j];
    for (int k = 0; k < 64; ++k) acc += x[(long)s  * 64 + k] * W1[k * 64 + j];
    for (int k = 0; k < 64; ++k) acc += x[(long)dd * 64 + k] * W1[(64 + k) * 64 + j];
    for (int k = 0; k < 16; ++k) acc += edge_attr[e * 16 + k] * W1[(128 + k) * 64 + j];
    const float h = fmaxf(acc, 0.f);

    float msg = b2[j];
    for (int k = 0; k < 64; ++k) msg += __shfl(h, k) * W2[k * 64 + j];
    unsafeAtomicAdd(&out[(long)dd * 64 + j], msg);
}

extern "C" void kernel_launch(void* const* d_in, const int* in_sizes, int n_in,
                              void* d_out, int out_size, void* d_ws, size_t ws_size,
                              hipStream_t stream) {
    const float* x   = (const float*)d_in[0];
    const int*   ei  = (const int*)d_in[1];
    const float* ea  = (const float*)d_in[2];
    const float* W1  = (const float*)d_in[3];
    const float* b1  = (const float*)d_in[4];
    const float* W2  = (const float*)d_in[5];
    const float* b2  = (const float*)d_in[6];
    float* out = (float*)d_out;

    const size_t NF = (size_t)N_NODES * 64;
    const size_t need_new = 3 * NF * 4                  // xa, xb, hsum
                          + (size_t)N_NODES * 4 + 256   // cnt, ocnt(+pad)
                          + (size_t)N_NODES * CAP * 8   // slot (uint2)
                          + (size_t)N_EDGES * 4;        // oflow
    const size_t need_old = 2 * NF * 4;

    if (ws_size >= need_new) {
        char* p = (char*)d_ws;
        float*    xauf  = (float*)p;    p += NF * 4;
        float*    xbuf  = (float*)p;    p += NF * 4;
        float*    hsum  = (float*)p;    p += NF * 4;
        unsigned* cnt   = (unsigned*)p; p += (size_t)N_NODES * 4;
        unsigned* ocnt  = (unsigned*)p; p += 256;
        uint2*    slot  = (uint2*)p;    p += (size_t)N_NODES * CAP * 8;
        unsigned* oflow = (unsigned*)p;

        hipMemsetAsync(cnt, 0, (size_t)N_NODES * 4 + 256, stream);
        pre_kernel<<<512, 256, 0, stream>>>(x, W1, xauf, xbuf);
        build_kernel<<<N_EDGES / 256, 256, 0, stream>>>(ei, cnt, ocnt, slot, oflow);
        node_kernel<<<N_NODES / 4, 256, 0, stream>>>(xauf, xbuf, ea, slot, cnt,
                                                     W1, b1, hsum);
        post_kernel<<<512, 256, 0, stream>>>(hsum, cnt, W2, b2, out);
        overflow_kernel<<<16, 256, 0, stream>>>(xauf, xbuf, ei, ea, W1, b1,
                                                W2, b2, ocnt, oflow, out);
    } else if (ws_size >= need_old) {
        hipMemsetAsync(out, 0, (size_t)N_NODES * 64 * sizeof(float), stream);
        float* xauf = (float*)d_ws;
        float* xbuf = xauf + NF;
        pre_kernel<<<512, 256, 0, stream>>>(x, W1, xauf, xbuf);
        edge_kernel<<<N_EDGES / 64, 256, 0, stream>>>(xauf, xbuf, ei, ea,
                                                      W1, b1, W2, b2, out);
    } else {
        hipMemsetAsync(out, 0, (size_t)N_NODES * 64 * sizeof(float), stream);
        fallback_kernel<<<N_EDGES / 4, 256, 0, stream>>>(x, ei, ea,
                                                         W1, b1, W2, b2, out);
    }
}

// Round 2
// 328.373 us; speedup vs baseline: 1.1510x; 1.1510x over previous
//
#include <hip/hip_runtime.h>

#define N_NODES 50000
#define N_EDGES 800000
#define CAP 48
// IN_F = 64, OUT_F = 64, EDGE_F = 16, d_in1 = 144
// NOTE: harness passes ALL integer inputs as int32 — edge_index is int32[2*E],
// src = ei[e], dst = ei[E+e].

// ---------------------------------------------------------------------------
// prebuild_kernel: fused.
//  blocks [0,512):    xa = x @ W1[0:64,:], xb = x @ W1[64:128,:]
//  blocks [512,3637): bucket edges by dst. slot[d*CAP+pos] = (src, e).
// cnt must be zeroed before launch (memsetAsync).
// ---------------------------------------------------------------------------
__global__ __launch_bounds__(256) void prebuild_kernel(
    const float* __restrict__ x, const float* __restrict__ W1,
    float* __restrict__ xa, float* __restrict__ xb,
    const int* __restrict__ ei, unsigned* __restrict__ cnt,
    unsigned* __restrict__ ocnt, uint2* __restrict__ slot,
    unsigned* __restrict__ oflow)
{
    if (blockIdx.x >= 512) {
        // ---- build part: one thread per edge ----
        const int e = (blockIdx.x - 512) * 256 + threadIdx.x;
        const int s = ei[e];
        const int d = ei[N_EDGES + e];
        const unsigned pos = atomicAdd(&cnt[d], 1u);
        if (pos < CAP) {
            slot[(size_t)d * CAP + pos] = make_uint2((unsigned)s, (unsigned)e);
        } else {
            const unsigned oi = atomicAdd(ocnt, 1u);
            oflow[oi] = (unsigned)e;
        }
        return;
    }
    // ---- pre part: wave per (node-subset, product) ----
    const int w = threadIdx.x >> 6;
    const int j = threadIdx.x & 63;
    const int gw = blockIdx.x * 4 + w;
    const int p = gw & 1;
    const int pair = gw >> 1;
    const int npair = 1024;   // 512 blocks * 4 waves / 2

    float wc[64];
#pragma unroll
    for (int k = 0; k < 64; ++k) wc[k] = W1[(p * 64 + k) * 64 + j];

    float* __restrict__ outp = p ? xb : xa;

    for (int i = pair; i < N_NODES; i += npair) {
        const float4* xr = (const float4*)&x[(size_t)i * 64];
        float acc = 0.f;
#pragma unroll
        for (int k4 = 0; k4 < 16; ++k4) {
            float4 xv = xr[k4];
            acc += xv.x * wc[k4 * 4 + 0];
            acc += xv.y * wc[k4 * 4 + 1];
            acc += xv.z * wc[k4 * 4 + 2];
            acc += xv.w * wc[k4 * 4 + 3];
        }
        outp[(size_t)i * 64 + j] = acc;
    }
}

// ---------------------------------------------------------------------------
// node_kernel: one wave per dst node. hsum[n] = sum_e relu(xa[src]+xb[n]+ea@W1c+b1)
// Wave-uniform restructure: the whole edge list is loaded in ONE coalesced
// load (lane j holds slot j); per-edge (src,e) come from v_readlane into
// SGPRs, so ea loads are uniform-address (s_load-promotable) and xa is
// saddr+lane addressing. Copy-free unroll-2 double-buffered pipeline.
// ---------------------------------------------------------------------------
__global__ __launch_bounds__(256) void node_kernel(
    const float* __restrict__ xa, const float* __restrict__ xb,
    const float* __restrict__ ea, const uint2* __restrict__ slot,
    const unsigned* __restrict__ cnt,
    const float* __restrict__ W1, const float* __restrict__ b1,
    float* __restrict__ hsum)
{
    const int w = threadIdx.x >> 6;
    const int j = threadIdx.x & 63;
    const int n = blockIdx.x * 4 + w;

    float w1c[16];
#pragma unroll
    for (int k = 0; k < 16; ++k) w1c[k] = W1[(128 + k) * 64 + j];
    const float base = xb[(size_t)n * 64 + j] + b1[j];

    const int deg = (int)cnt[n];
    const int dcap = deg < CAP ? deg : CAP;

    // one coalesced load fetches the whole bucket: lane j holds slot j
    uint2 my = make_uint2(0u, 0u);
    if (j < dcap) my = slot[(size_t)n * CAP + j];

    float hacc = 0.f;

#define LOADE(i, e0, e1, e2, e3, xv)                                        \
    {                                                                       \
        const unsigned se = (unsigned)__builtin_amdgcn_readlane((int)my.y, (i)); \
        const unsigned ss = (unsigned)__builtin_amdgcn_readlane((int)my.x, (i)); \
        const float4* eap = (const float4*)(ea + (size_t)se * 16);          \
        e0 = eap[0]; e1 = eap[1]; e2 = eap[2]; e3 = eap[3];                 \
        xv = xa[(size_t)ss * 64 + j];                                       \
    }

#define CONSUME(e0, e1, e2, e3, xv)                                         \
    {                                                                       \
        float acc = base + (xv);                                            \
        acc += (e0).x * w1c[0];  acc += (e0).y * w1c[1];                    \
        acc += (e0).z * w1c[2];  acc += (e0).w * w1c[3];                    \
        acc += (e1).x * w1c[4];  acc += (e1).y * w1c[5];                    \
        acc += (e1).z * w1c[6];  acc += (e1).w * w1c[7];                    \
        acc += (e2).x * w1c[8];  acc += (e2).y * w1c[9];                    \
        acc += (e2).z * w1c[10]; acc += (e2).w * w1c[11];                   \
        acc += (e3).x * w1c[12]; acc += (e3).y * w1c[13];                   \
        acc += (e3).z * w1c[14]; acc += (e3).w * w1c[15];                   \
        hacc += fmaxf(acc, 0.f);                                            \
    }

    if (dcap > 0) {
        float4 A0, A1, A2, A3; float Ax;
        float4 B0, B1, B2, B3; float Bx;
        LOADE(0, A0, A1, A2, A3, Ax);
        for (int i = 0; i < dcap; i += 2) {
            if (i + 1 < dcap) LOADE(i + 1, B0, B1, B2, B3, Bx);
            CONSUME(A0, A1, A2, A3, Ax);
            if (i + 2 < dcap) LOADE(i + 2, A0, A1, A2, A3, Ax);
            if (i + 1 < dcap) CONSUME(B0, B1, B2, B3, Bx);
        }
    }
#undef LOADE
#undef CONSUME

    hsum[(size_t)n * 64 + j] = hacc;
}

// ---------------------------------------------------------------------------
// post_kernel: out[n] = hsum[n] @ W2 + min(cnt[n],CAP) * b2
// ---------------------------------------------------------------------------
__global__ __launch_bounds__(256) void post_kernel(
    const float* __restrict__ hsum, const unsigned* __restrict__ cnt,
    const float* __restrict__ W2, const float* __restrict__ b2,
    float* __restrict__ out)
{
    const int w = threadIdx.x >> 6;
    const int j = threadIdx.x & 63;
    const int gw = blockIdx.x * 4 + w;
    const int nw = gridDim.x * 4;

    float w2c[64];
#pragma unroll
    for (int k = 0; k < 64; ++k) w2c[k] = W2[k * 64 + j];
    const float b2j = b2[j];

    for (int n = gw; n < N_NODES; n += nw) {
        const float4* hr = (const float4*)&hsum[(size_t)n * 64];
        float acc = 0.f;
#pragma unroll
        for (int k4 = 0; k4 < 16; ++k4) {
            float4 hv = hr[k4];
            acc += hv.x * w2c[k4 * 4 + 0];
            acc += hv.y * w2c[k4 * 4 + 1];
            acc += hv.z * w2c[k4 * 4 + 2];
            acc += hv.w * w2c[k4 * 4 + 3];
        }
        int d = (int)cnt[n];
        d = d < CAP ? d : CAP;
        out[(size_t)n * 64 + j] = acc + (float)d * b2j;
    }
}

// ---------------------------------------------------------------------------
// overflow_kernel: correctness net for pos >= CAP edges (expected 0 edges).
// Runs AFTER post_kernel; adds its own b2 per overflow edge.
// ---------------------------------------------------------------------------
__global__ __launch_bounds__(256) void overflow_kernel(
    const float* __restrict__ xa, const float* __restrict__ xb,
    const int* __restrict__ ei, const float* __restrict__ ea,
    const float* __restrict__ W1, const float* __restrict__ b1,
    const float* __restrict__ W2, const float* __restrict__ b2,
    const unsigned* __restrict__ ocnt, const unsigned* __restrict__ oflow,
    float* __restrict__ out)
{
    const unsigned oc = *ocnt;
    if (oc == 0) return;
    const int w = threadIdx.x >> 6;
    const int j = threadIdx.x & 63;
    unsigned idx = blockIdx.x * 4 + w;
    const unsigned stride = gridDim.x * 4;
    for (; idx < oc; idx += stride) {
        const int e = (int)oflow[idx];
        const int s = ei[e];
        const int dd = ei[N_EDGES + e];
        float acc = xa[(size_t)s * 64 + j] + xb[(size_t)dd * 64 + j] + b1[j];
        for (int k = 0; k < 16; ++k)
            acc += ea[(size_t)e * 16 + k] * W1[(128 + k) * 64 + j];
        const float h = fmaxf(acc, 0.f);
        float msg = b2[j];
        for (int k = 0; k < 64; ++k) msg += __shfl(h, k) * W2[k * 64 + j];
        unsafeAtomicAdd(&out[(size_t)dd * 64 + j], msg);
    }
}

// ---------------------------------------------------------------------------
// OLD PATH (ws too small for bucketed pipeline): per-edge kernel with atomics.
// ---------------------------------------------------------------------------
__global__ __launch_bounds__(256) void pre_kernel(
    const float* __restrict__ x, const float* __restrict__ W1,
    float* __restrict__ xa, float* __restrict__ xb)
{
    const int w = threadIdx.x >> 6;
    const int j = threadIdx.x & 63;
    const int gw = blockIdx.x * 4 + w;
    const int p = gw & 1;
    const int pair = gw >> 1;
    const int npair = (gridDim.x * 4) >> 1;

    float wc[64];
#pragma unroll
    for (int k = 0; k < 64; ++k) wc[k] = W1[(p * 64 + k) * 64 + j];

    float* __restrict__ outp = p ? xb : xa;

    for (int i = pair; i < N_NODES; i += npair) {
        const float4* xr = (const float4*)&x[(size_t)i * 64];
        float acc = 0.f;
#pragma unroll
        for (int k4 = 0; k4 < 16; ++k4) {
            float4 xv = xr[k4];
            acc += xv.x * wc[k4 * 4 + 0];
            acc += xv.y * wc[k4 * 4 + 1];
            acc += xv.z * wc[k4 * 4 + 2];
            acc += xv.w * wc[k4 * 4 + 3];
        }
        outp[(size_t)i * 64 + j] = acc;
    }
}

__global__ __launch_bounds__(256) void edge_kernel(
    const float* __restrict__ xa, const float* __restrict__ xb,
    const int* __restrict__ ei,
    const float* __restrict__ edge_attr,
    const float* __restrict__ W1, const float* __restrict__ b1,
    const float* __restrict__ W2, const float* __restrict__ b2,
    float* __restrict__ out)
{
    __shared__ __align__(16) float eas[4][256];
    __shared__ __align__(16) float hs[4][16][64];

    const int w = threadIdx.x >> 6;
    const int j = threadIdx.x & 63;
    const int wt = blockIdx.x * 4 + w;
    const long eb = (long)wt * 16;

    float w1c[16];
    float w2c[64];
#pragma unroll
    for (int k = 0; k < 16; ++k) w1c[k] = W1[(128 + k) * 64 + j];
#pragma unroll
    for (int k = 0; k < 64; ++k) w2c[k] = W2[k * 64 + j];
    const float b1j = b1[j];
    const float b2j = b2[j];

    int idxv = 0;
    if (j < 16)       idxv = ei[eb + j];
    else if (j < 32)  idxv = ei[(long)N_EDGES + eb + (j - 16)];

    {
        float4 ev = *(const float4*)&edge_attr[eb * 16 + j * 4];
        *(float4*)&eas[w][j * 4] = ev;
    }

#pragma unroll 4
    for (int e = 0; e < 16; ++e) {
        const int s  = __shfl(idxv, e);
        const int dd = __shfl(idxv, 16 + e);

        float acc = xa[(long)s * 64 + j] + xb[(long)dd * 64 + j] + b1j;
#pragma unroll
        for (int k4 = 0; k4 < 4; ++k4) {
            float4 ev = *(const float4*)&eas[w][e * 16 + k4 * 4];
            acc += ev.x * w1c[k4 * 4 + 0];
            acc += ev.y * w1c[k4 * 4 + 1];
            acc += ev.z * w1c[k4 * 4 + 2];
            acc += ev.w * w1c[k4 * 4 + 3];
        }
        const float h = fmaxf(acc, 0.f);
        hs[w][e][j] = h;

        float msg = b2j;
#pragma unroll
        for (int k4 = 0; k4 < 16; ++k4) {
            float4 hv = *(const float4*)&hs[w][e][k4 * 4];
            msg += hv.x * w2c[k4 * 4 + 0];
            msg += hv.y * w2c[k4 * 4 + 1];
            msg += hv.z * w2c[k4 * 4 + 2];
            msg += hv.w * w2c[k4 * 4 + 3];
        }
        unsafeAtomicAdd(&out[(long)dd * 64 + j], msg);
    }
}

__global__ __launch_bounds__(256) void fallback_kernel(
    const float* __restrict__ x, const int* __restrict__ ei,
    const float* __restrict__ edge_attr,
    const float* __restrict__ W1, const float* __restrict__ b1,
    const float* __restrict__ W2, const float* __restrict__ b2,
    float* __restrict__ out)
{
    const int w = threadIdx.x >> 6;
    const int j = threadIdx.x & 63;
    const long e = (long)blockIdx.x * 4 + w;
    if (e >= N_EDGES) return;
    const int s  = ei[e];
    const int dd = ei[(long)N_EDGES + e];

    float acc = b1[j];
    for (int k = 0; k < 64; ++k) acc += x[(long)s  * 64 + k] * W1[k * 64 + j];
    for (int k = 0; k < 64; ++k) acc += x[(long)dd * 64 + k] * W1[(64 + k) * 64 + j];
    for (int k = 0; k < 16; ++k) acc += edge_attr[e * 16 + k] * W1[(128 + k) * 64 + j];
    const float h = fmaxf(acc, 0.f);

    float msg = b2[j];
    for (int k = 0; k < 64; ++k) msg += __shfl(h, k) * W2[k * 64 + j];
    unsafeAtomicAdd(&out[(long)dd * 64 + j], msg);
}

extern "C" void kernel_launch(void* const* d_in, const int* in_sizes, int n_in,
                              void* d_out, int out_size, void* d_ws, size_t ws_size,
                              hipStream_t stream) {
    const float* x   = (const float*)d_in[0];
    const int*   ei  = (const int*)d_in[1];
    const float* ea  = (const float*)d_in[2];
    const float* W1  = (const float*)d_in[3];
    const float* b1  = (const float*)d_in[4];
    const float* W2  = (const float*)d_in[5];
    const float* b2  = (const float*)d_in[6];
    float* out = (float*)d_out;

    const size_t NF = (size_t)N_NODES * 64;
    const size_t need_new = 3 * NF * 4                  // xa, xb, hsum
                          + (size_t)N_NODES * 4 + 256   // cnt, ocnt(+pad)
                          + (size_t)N_NODES * CAP * 8   // slot (uint2)
                          + (size_t)N_EDGES * 4;        // oflow
    const size_t need_old = 2 * NF * 4;

    if (ws_size >= need_new) {
        char* p = (char*)d_ws;
        float*    xauf  = (float*)p;    p += NF * 4;
        float*    xbuf  = (float*)p;    p += NF * 4;
        float*    hsum  = (float*)p;    p += NF * 4;
        unsigned* cnt   = (unsigned*)p; p += (size_t)N_NODES * 4;
        unsigned* ocnt  = (unsigned*)p; p += 256;
        uint2*    slot  = (uint2*)p;    p += (size_t)N_NODES * CAP * 8;
        unsigned* oflow = (unsigned*)p;

        hipMemsetAsync(cnt, 0, (size_t)N_NODES * 4 + 256, stream);
        prebuild_kernel<<<512 + N_EDGES / 256, 256, 0, stream>>>(
            x, W1, xauf, xbuf, ei, cnt, ocnt, slot, oflow);
        node_kernel<<<N_NODES / 4, 256, 0, stream>>>(xauf, xbuf, ea, slot, cnt,
                                                     W1, b1, hsum);
        post_kernel<<<1024, 256, 0, stream>>>(hsum, cnt, W2, b2, out);
        overflow_kernel<<<16, 256, 0, stream>>>(xauf, xbuf, ei, ea, W1, b1,
                                                W2, b2, ocnt, oflow, out);
    } else if (ws_size >= need_old) {
        hipMemsetAsync(out, 0, (size_t)N_NODES * 64 * sizeof(float), stream);
        float* xauf = (float*)d_ws;
        float* xbuf = xauf + NF;
        pre_kernel<<<512, 256, 0, stream>>>(x, W1, xauf, xbuf);
        edge_kernel<<<N_EDGES / 64, 256, 0, stream>>>(xauf, xbuf, ei, ea,
                                                      W1, b1, W2, b2, out);
    } else {
        hipMemsetAsync(out, 0, (size_t)N_NODES * 64 * sizeof(float), stream);
        fallback_kernel<<<N_EDGES / 4, 256, 0, stream>>>(x, ei, ea,
                                                         W1, b1, W2, b2, out);
    }
}

// Round 4
// 269.125 us; speedup vs baseline: 1.4043x; 1.2202x over previous
//
#include <hip/hip_runtime.h>

#define N_NODES 50000
#define N_EDGES 800000
#define CAP 48
// IN_F = 64, OUT_F = 64, EDGE_F = 16, d_in1 = 144
// NOTE: harness passes ALL integer inputs as int32 — edge_index is int32[2*E],
// src = ei[e], dst = ei[E+e].
// NOTE (round 3): hipLaunchCooperativeKernel inside kernel_launch broke the
// harness (graph capture) — container failed twice. DO NOT use coop launch.

#define FMA16(acc, ep, wreg)                                                 \
    {                                                                        \
        float4 _e0 = (ep)[0], _e1 = (ep)[1], _e2 = (ep)[2], _e3 = (ep)[3];   \
        acc += _e0.x * wreg[0];  acc += _e0.y * wreg[1];                     \
        acc += _e0.z * wreg[2];  acc += _e0.w * wreg[3];                     \
        acc += _e1.x * wreg[4];  acc += _e1.y * wreg[5];                     \
        acc += _e1.z * wreg[6];  acc += _e1.w * wreg[7];                     \
        acc += _e2.x * wreg[8];  acc += _e2.y * wreg[9];                     \
        acc += _e2.z * wreg[10]; acc += _e2.w * wreg[11];                    \
        acc += _e3.x * wreg[12]; acc += _e3.y * wreg[13];                    \
        acc += _e3.z * wreg[14]; acc += _e3.w * wreg[15];                    \
    }

// ---------------------------------------------------------------------------
// prebuild_kernel: fused.
//  blocks [0,512):    xa = x @ W1[0:64,:], xb = x @ W1[64:128,:]
//  blocks [512,3637): bucket edges by dst. slot[d*CAP+pos] = (src, e).
// cnt must be zeroed before launch (memsetAsync).
// ---------------------------------------------------------------------------
__global__ __launch_bounds__(256) void prebuild_kernel(
    const float* __restrict__ x, const float* __restrict__ W1,
    float* __restrict__ xa, float* __restrict__ xb,
    const int* __restrict__ ei, unsigned* __restrict__ cnt,
    unsigned* __restrict__ ocnt, uint2* __restrict__ slot,
    unsigned* __restrict__ oflow)
{
    if (blockIdx.x >= 512) {
        const int e = (blockIdx.x - 512) * 256 + threadIdx.x;
        const int s = ei[e];
        const int d = ei[N_EDGES + e];
        const unsigned pos = atomicAdd(&cnt[d], 1u);
        if (pos < CAP) {
            slot[(size_t)d * CAP + pos] = make_uint2((unsigned)s, (unsigned)e);
        } else {
            const unsigned oi = atomicAdd(ocnt, 1u);
            oflow[oi] = (unsigned)e;
        }
        return;
    }
    const int w = threadIdx.x >> 6;
    const int j = threadIdx.x & 63;
    const int gw = blockIdx.x * 4 + w;
    const int p = gw & 1;          // 0 -> xa, 1 -> xb
    const int pair = gw >> 1;
    const int npair = 1024;        // 512 blocks * 4 waves / 2

    float wc[64];
#pragma unroll
    for (int k = 0; k < 64; ++k) wc[k] = W1[(p * 64 + k) * 64 + j];
    float* __restrict__ outp = p ? xb : xa;
    for (int i = pair; i < N_NODES; i += npair) {
        const float4* xr = (const float4*)&x[(size_t)i * 64];
        float acc = 0.f;
#pragma unroll
        for (int k4 = 0; k4 < 16; ++k4) {
            float4 xv = xr[k4];
            acc += xv.x * wc[k4 * 4 + 0];
            acc += xv.y * wc[k4 * 4 + 1];
            acc += xv.z * wc[k4 * 4 + 2];
            acc += xv.w * wc[k4 * 4 + 3];
        }
        outp[(size_t)i * 64 + j] = acc;
    }
}

// ---------------------------------------------------------------------------
// nodefused_kernel: one wave per dst node.
//   hacc = sum_e relu(xa[src]+xb[n]+ea@W1c+b1)    (aggregation)
//   out[n] = hacc @ W2 + dcap*b2                  (W2 hoisted out of seg-sum)
// Chunked depth-16 memory parallelism: per 16-edge chunk, stage the 16 ea
// rows with one b128 load per lane (lane l -> edge l>>2, quarter l&3) into
// LDS, issue all 16 xa gathers into unrolled named registers, then consume
// via broadcast ds_read_b128 + 16 FMA per edge.
// ---------------------------------------------------------------------------
__global__ __launch_bounds__(256) void nodefused_kernel(
    const float* __restrict__ xa, const float* __restrict__ xb,
    const float* __restrict__ ea, const uint2* __restrict__ slot,
    const unsigned* __restrict__ cnt,
    const float* __restrict__ W1, const float* __restrict__ b1,
    const float* __restrict__ W2, const float* __restrict__ b2,
    float* __restrict__ out)
{
    __shared__ __align__(16) float sea[4][CAP * 16];   // 12 KB / block

    const int w = threadIdx.x >> 6;
    const int j = threadIdx.x & 63;
    const int n = blockIdx.x * 4 + w;

    float w1c[16];
#pragma unroll
    for (int k = 0; k < 16; ++k) w1c[k] = W1[(128 + k) * 64 + j];
    const float b1j = b1[j];
    const float b2j = b2[j];

    const int deg = (int)cnt[n];
    const int dcap = deg < CAP ? deg : CAP;

    uint2 my = make_uint2(0u, 0u);
    if (j < dcap) my = slot[(size_t)n * CAP + j];     // lane j holds slot j

    const float base = xb[(size_t)n * 64 + j] + b1j;

    float hacc = 0.f;
    if (dcap > 0) {
        const int sub = j >> 2;        // which edge of the chunk this lane stages
        const int q   = j & 3;         // which float4 quarter of that edge

        for (int b0 = 0; b0 < dcap; b0 += 16) {
            // ---- stage ea rows of edges b0..b0+15 into LDS (1 b128/lane) ----
            {
                int ii = b0 + sub;
                const int ic = ii < dcap ? ii : dcap - 1;   // clamp: benign dup
                const unsigned eid = (unsigned)__shfl((int)my.y, ic);
                float4 v = *(const float4*)(ea + (size_t)eid * 16 + q * 4);
                *(float4*)&sea[w][ic * 16 + q * 4] = v;
            }
            // ---- issue 16 xa gathers into registers (static indexing) ----
            float xv[16];
#pragma unroll
            for (int t = 0; t < 16; ++t) {
                int ii = b0 + t;
                const int ic = ii < dcap ? ii : dcap - 1;   // uniform select
                const unsigned ss =
                    (unsigned)__builtin_amdgcn_readlane((int)my.x, ic);
                xv[t] = xa[(size_t)ss * 64 + j];
            }
            // ---- consume 16 edges ----
#pragma unroll
            for (int t = 0; t < 16; ++t) {
                const int ii = b0 + t;
                if (ii < dcap) {                            // uniform branch
                    const float4* ep = (const float4*)&sea[w][ii * 16];
                    float acc = base + xv[t];
                    FMA16(acc, ep, w1c);
                    hacc += fmaxf(acc, 0.f);
                }
            }
        }
    }

    // ---- fused epilogue: out[n] = hacc @ W2 + dcap * b2 ----
    // broadcast hacc across lanes through LDS (reuse sea; wave-internal)
    sea[w][j] = hacc;
    float msg = (float)dcap * b2j;
#pragma unroll
    for (int k4 = 0; k4 < 16; ++k4) {
        float4 hv = *(const float4*)&sea[w][k4 * 4];        // uniform broadcast
        msg += hv.x * W2[(k4 * 4 + 0) * 64 + j];
        msg += hv.y * W2[(k4 * 4 + 1) * 64 + j];
        msg += hv.z * W2[(k4 * 4 + 2) * 64 + j];
        msg += hv.w * W2[(k4 * 4 + 3) * 64 + j];
    }
    out[(size_t)n * 64 + j] = msg;
}

// ---------------------------------------------------------------------------
// overflow_kernel: correctness net for pos >= CAP edges (expected 0 edges).
// Runs AFTER nodefused (stream order); adds full W2-transformed message + b2.
// ---------------------------------------------------------------------------
__global__ __launch_bounds__(256) void overflow_kernel(
    const float* __restrict__ xa, const float* __restrict__ xb,
    const int* __restrict__ ei, const float* __restrict__ ea,
    const float* __restrict__ W1, const float* __restrict__ b1,
    const float* __restrict__ W2, const float* __restrict__ b2,
    const unsigned* __restrict__ ocnt, const unsigned* __restrict__ oflow,
    float* __restrict__ out)
{
    const unsigned oc = *ocnt;
    if (oc == 0) return;
    const int w = threadIdx.x >> 6;
    const int j = threadIdx.x & 63;
    unsigned idx = blockIdx.x * 4 + w;
    const unsigned stride = gridDim.x * 4;
    for (; idx < oc; idx += stride) {
        const int e = (int)oflow[idx];
        const int s = ei[e];
        const int dd = ei[N_EDGES + e];
        float acc = xa[(size_t)s * 64 + j] + xb[(size_t)dd * 64 + j] + b1[j];
        for (int k = 0; k < 16; ++k)
            acc += ea[(size_t)e * 16 + k] * W1[(128 + k) * 64 + j];
        const float h = fmaxf(acc, 0.f);
        float msg = b2[j];
        for (int k = 0; k < 64; ++k) msg += __shfl(h, k) * W2[k * 64 + j];
        unsafeAtomicAdd(&out[(size_t)dd * 64 + j], msg);
    }
}

// ---------------------------------------------------------------------------
// OLD PATH kernels (ws too small for bucketed pipeline)
// ---------------------------------------------------------------------------
__global__ __launch_bounds__(256) void pre_kernel(
    const float* __restrict__ x, const float* __restrict__ W1,
    float* __restrict__ xa, float* __restrict__ xb)
{
    const int w = threadIdx.x >> 6;
    const int j = threadIdx.x & 63;
    const int gw = blockIdx.x * 4 + w;
    const int p = gw & 1;
    const int pair = gw >> 1;
    const int npair = (gridDim.x * 4) >> 1;

    float wc[64];
#pragma unroll
    for (int k = 0; k < 64; ++k) wc[k] = W1[(p * 64 + k) * 64 + j];
    float* __restrict__ outp = p ? xb : xa;
    for (int i = pair; i < N_NODES; i += npair) {
        const float4* xr = (const float4*)&x[(size_t)i * 64];
        float acc = 0.f;
#pragma unroll
        for (int k4 = 0; k4 < 16; ++k4) {
            float4 xv = xr[k4];
            acc += xv.x * wc[k4 * 4 + 0];
            acc += xv.y * wc[k4 * 4 + 1];
            acc += xv.z * wc[k4 * 4 + 2];
            acc += xv.w * wc[k4 * 4 + 3];
        }
        outp[(size_t)i * 64 + j] = acc;
    }
}

__global__ __launch_bounds__(256) void edge_kernel(
    const float* __restrict__ xa, const float* __restrict__ xb,
    const int* __restrict__ ei,
    const float* __restrict__ edge_attr,
    const float* __restrict__ W1, const float* __restrict__ b1,
    const float* __restrict__ W2, const float* __restrict__ b2,
    float* __restrict__ out)
{
    __shared__ __align__(16) float eas[4][256];
    __shared__ __align__(16) float hs[4][16][64];

    const int w = threadIdx.x >> 6;
    const int j = threadIdx.x & 63;
    const int wt = blockIdx.x * 4 + w;
    const long eb = (long)wt * 16;

    float w1c[16];
    float w2c[64];
#pragma unroll
    for (int k = 0; k < 16; ++k) w1c[k] = W1[(128 + k) * 64 + j];
#pragma unroll
    for (int k = 0; k < 64; ++k) w2c[k] = W2[k * 64 + j];
    const float b1j = b1[j];
    const float b2j = b2[j];

    int idxv = 0;
    if (j < 16)       idxv = ei[eb + j];
    else if (j < 32)  idxv = ei[(long)N_EDGES + eb + (j - 16)];

    {
        float4 ev = *(const float4*)&edge_attr[eb * 16 + j * 4];
        *(float4*)&eas[w][j * 4] = ev;
    }

#pragma unroll 4
    for (int e = 0; e < 16; ++e) {
        const int s  = __shfl(idxv, e);
        const int dd = __shfl(idxv, 16 + e);

        float acc = xa[(long)s * 64 + j] + xb[(long)dd * 64 + j] + b1j;
#pragma unroll
        for (int k4 = 0; k4 < 4; ++k4) {
            float4 ev = *(const float4*)&eas[w][e * 16 + k4 * 4];
            acc += ev.x * w1c[k4 * 4 + 0];
            acc += ev.y * w1c[k4 * 4 + 1];
            acc += ev.z * w1c[k4 * 4 + 2];
            acc += ev.w * w1c[k4 * 4 + 3];
        }
        const float h = fmaxf(acc, 0.f);
        hs[w][e][j] = h;

        float msg = b2j;
#pragma unroll
        for (int k4 = 0; k4 < 16; ++k4) {
            float4 hv = *(const float4*)&hs[w][e][k4 * 4];
            msg += hv.x * w2c[k4 * 4 + 0];
            msg += hv.y * w2c[k4 * 4 + 1];
            msg += hv.z * w2c[k4 * 4 + 2];
            msg += hv.w * w2c[k4 * 4 + 3];
        }
        unsafeAtomicAdd(&out[(long)dd * 64 + j], msg);
    }
}

__global__ __launch_bounds__(256) void fallback_kernel(
    const float* __restrict__ x, const int* __restrict__ ei,
    const float* __restrict__ edge_attr,
    const float* __restrict__ W1, const float* __restrict__ b1,
    const float* __restrict__ W2, const float* __restrict__ b2,
    float* __restrict__ out)
{
    const int w = threadIdx.x >> 6;
    const int j = threadIdx.x & 63;
    const long e = (long)blockIdx.x * 4 + w;
    if (e >= N_EDGES) return;
    const int s  = ei[e];
    const int dd = ei[(long)N_EDGES + e];

    float acc = b1[j];
    for (int k = 0; k < 64; ++k) acc += x[(long)s  * 64 + k] * W1[k * 64 + j];
    for (int k = 0; k < 64; ++k) acc += x[(long)dd * 64 + k] * W1[(64 + k) * 64 + j];
    for (int k = 0; k < 16; ++k) acc += edge_attr[e * 16 + k] * W1[(128 + k) * 64 + j];
    const float h = fmaxf(acc, 0.f);

    float msg = b2[j];
    for (int k = 0; k < 64; ++k) msg += __shfl(h, k) * W2[k * 64 + j];
    unsafeAtomicAdd(&out[(long)dd * 64 + j], msg);
}

extern "C" void kernel_launch(void* const* d_in, const int* in_sizes, int n_in,
                              void* d_out, int out_size, void* d_ws, size_t ws_size,
                              hipStream_t stream) {
    const float* x   = (const float*)d_in[0];
    const int*   ei  = (const int*)d_in[1];
    const float* ea  = (const float*)d_in[2];
    const float* W1  = (const float*)d_in[3];
    const float* b1  = (const float*)d_in[4];
    const float* W2  = (const float*)d_in[5];
    const float* b2  = (const float*)d_in[6];
    float* out = (float*)d_out;

    const size_t NF = (size_t)N_NODES * 64;
    const size_t need_main = 2 * NF * 4                    // xa, xb
                           + (size_t)N_NODES * 4 + 256     // cnt, ocnt(+pad)
                           + (size_t)N_NODES * CAP * 8     // slot (uint2)
                           + (size_t)N_EDGES * 4;          // oflow
    const size_t need_old = 2 * NF * 4;

    if (ws_size >= need_main) {
        char* p = (char*)d_ws;
        float*    xauf  = (float*)p;    p += NF * 4;
        float*    xbuf  = (float*)p;    p += NF * 4;
        unsigned* cnt   = (unsigned*)p; p += (size_t)N_NODES * 4;
        unsigned* ocnt  = (unsigned*)p; p += 256;
        uint2*    slot  = (uint2*)p;    p += (size_t)N_NODES * CAP * 8;
        unsigned* oflow = (unsigned*)p;

        hipMemsetAsync(cnt, 0, (size_t)N_NODES * 4 + 256, stream);
        prebuild_kernel<<<512 + N_EDGES / 256, 256, 0, stream>>>(
            x, W1, xauf, xbuf, ei, cnt, ocnt, slot, oflow);
        nodefused_kernel<<<N_NODES / 4, 256, 0, stream>>>(
            xauf, xbuf, ea, slot, cnt, W1, b1, W2, b2, out);
        overflow_kernel<<<16, 256, 0, stream>>>(xauf, xbuf, ei, ea, W1, b1,
                                                W2, b2, ocnt, oflow, out);
    } else if (ws_size >= need_old) {
        hipMemsetAsync(out, 0, (size_t)N_NODES * 64 * sizeof(float), stream);
        float* xauf = (float*)d_ws;
        float* xbuf = xauf + NF;
        pre_kernel<<<512, 256, 0, stream>>>(x, W1, xauf, xbuf);
        edge_kernel<<<N_EDGES / 64, 256, 0, stream>>>(xauf, xbuf, ei, ea,
                                                      W1, b1, W2, b2, out);
    } else {
        hipMemsetAsync(out, 0, (size_t)N_NODES * 64 * sizeof(float), stream);
        fallback_kernel<<<N_EDGES / 4, 256, 0, stream>>>(x, ei, ea,
                                                         W1, b1, W2, b2, out);
    }
}